// Round 14
// baseline (68.142 us; speedup 1.0000x reference)
//
#include <hip/hip_runtime.h>
#include <math.h>

#define NQ 4096
#define NT 16384
#define DD 32
#define COLIDX 0
#define BIGF 1.0e10f
#define INFF __builtin_inff()

typedef unsigned long long u64;

#define ROW_VECS (NT / 4)                 // 4096 float4 per row
#define ROWS_PER_BLOCK 2
#define P1_BLOCKS (NQ / ROWS_PER_BLOCK)   // 2048 blocks = 8 blocks/CU

// Sentinel: larger (as u64/f64) than any real packed key; positive non-NaN f64.
#define SENT_BITS 0x7F800000FFFFFFFFULL

// ---------------------------------------------------------------------------
// bool-width helpers (unknown numpy bool storage: u8 vs i32)
// ---------------------------------------------------------------------------
__device__ __forceinline__ int boolat(const void* p, long long idx, int w32) {
    if (w32) return ((const int*)p)[idx] != 0;
    return ((const unsigned char*)p)[idx] != 0;
}

__device__ __forceinline__ int detect_w32(const void* nm, const void* mk,
                                          int tid, int* s_bad) {
    if (tid == 0) *s_bad = 0;
    __syncthreads();
    const unsigned char* nm8 = (const unsigned char*)nm;
    const unsigned char* mk8 = (const unsigned char*)mk;
    int bad = 0;
    for (int b = tid; b < 4096; b += 256)
        if ((int)nm8[b] + (int)mk8[b] != 1) bad = 1;
    if (bad) atomicOr(s_bad, 1);
    __syncthreads();
    return *s_bad ? 1 : 0;
}

// ---------------------------------------------------------------------------
// prep1: 64 blocks x 256 threads — pot8 pack, colmean partials, inmiss clear.
// (validated rounds 2-13)
// ---------------------------------------------------------------------------
__global__ __launch_bounds__(256) void prep1_kernel(
    const void* __restrict__ nm, const void* __restrict__ mk,
    const float* __restrict__ fitX,
    int* __restrict__ wflag, float* __restrict__ partial,
    unsigned char* __restrict__ inmiss, unsigned char* __restrict__ pot8)
{
    __shared__ int s_bad;
    __shared__ float sc[256], sm[256];
    const int tid = threadIdx.x;
    const int w32 = detect_w32(nm, mk, tid, &s_bad);
    if (blockIdx.x == 0 && tid == 0) *wflag = w32;

    const int t = blockIdx.x * 256 + tid;          // 0..16383
    pot8[t] = (unsigned char)boolat(nm, (long long)t * DD + COLIDX, w32);

    float cs = 0.0f, ms = 0.0f;
    if (!boolat(mk, (long long)t * DD + COLIDX, w32)) {
        cs = fitX[(long long)t * DD + COLIDX];
        ms = 1.0f;
    }
    sc[tid] = cs; sm[tid] = ms;
    __syncthreads();
#pragma unroll
    for (int s = 128; s > 0; s >>= 1) {
        if (tid < s) { sc[tid] += sc[tid + s]; sm[tid] += sm[tid + s]; }
        __syncthreads();
    }
    if (tid == 0) { partial[blockIdx.x * 2] = sc[0]; partial[blockIdx.x * 2 + 1] = sm[0]; }

    if (t < NQ) inmiss[t] = 0;
}

// prep2: scatter inmiss; colmean via 64-lane shuffle reduce (fixed order ->
// deterministic; replaces tid0's serial 64-load latency chain).
__global__ __launch_bounds__(256) void prep2_kernel(
    const int* __restrict__ rmi, const float* __restrict__ partial,
    float* __restrict__ cmean, unsigned char* __restrict__ inmiss)
{
    const int tid = threadIdx.x;
    for (int i = tid; i < NQ; i += 256) {
        int r = rmi[i];
        if (r >= 0 && r < NQ) inmiss[r] = 1;
    }
    if (tid < 64) {
        float c = partial[2 * tid];
        float m = partial[2 * tid + 1];
#pragma unroll
        for (int off = 32; off >= 1; off >>= 1) {
            c += __shfl_down(c, off, 64);
            m += __shfl_down(m, off, 64);
        }
        if (tid == 0) *cmean = c / (m > 0.0f ? m : 1.0f);
    }
}

// ---------------------------------------------------------------------------
// f64-packed key trick (validated round 13): packed (key_bits<<32)|idx viewed
// as double is always a POSITIVE NON-NAN f64 (NaN f32 keys excluded by fminf)
// -> numeric order == bit order == exact (key asc, idx asc) top_k order.
// v_min_f64/v_max_f64 = 1 inst each vs 3/5 for u64 compare+selects.
// ---------------------------------------------------------------------------
__device__ __forceinline__ double mkkeyd(float d, unsigned char p, unsigned idx) {
    const float key = (p != 0) ? fminf(d, BIGF) : INFF;  // NaN->BIG; !pot->INF
    const u64 bits = ((u64)__float_as_uint(key) << 32) | (u64)idx;
    return __longlong_as_double((long long)bits);
}

__device__ __forceinline__ void casd(double& x, double& y) {
    const double lo = fmin(x, y);
    const double hi = fmax(x, y);
    x = lo; y = hi;
}

// Merge two ascending sorted-5 lists, keep lowest 5, output sorted
// (network validated rounds 6-13).
__device__ __forceinline__ void merge5d(double a[5], const double b[5]) {
    double m0 = fmin(a[0], b[4]);
    double m1 = fmin(a[1], b[3]);
    double m2 = fmin(a[2], b[2]);
    double m3 = fmin(a[3], b[1]);
    double m4 = fmin(a[4], b[0]);
    casd(m0, m4);
    casd(m1, m3); casd(m2, m4);
    casd(m1, m2); casd(m3, m4);
    a[0] = m0; a[1] = m1; a[2] = m2; a[3] = m3; a[4] = m4;
}

// ---------------------------------------------------------------------------
// Pass 1: round-13 structure + wave-uniform network skip. For each 4-group,
// if NO lane has a candidate below its current 5th-best (gmin >= v[4]
// wave-wide), the sort4+merge networks are skipped — lanes without hits
// would pass through unchanged, so skipping is exact. Steady-state hit rate
// ~10-15% -> ~43% fewer VALU ops at identical memory pattern.
// ---------------------------------------------------------------------------
__global__ __launch_bounds__(256, 8) void pass1_kernel(
    const float* __restrict__ dist,
    const unsigned char* __restrict__ pot8,
    u64* __restrict__ wslists)
{
    __shared__ double sv[3][5];
    const int tid = threadIdx.x;
    const uchar4* pvec = (const uchar4*)pot8;
    const double SENT = __longlong_as_double((long long)SENT_BITS);

#pragma unroll 1
    for (int rr = 0; rr < ROWS_PER_BLOCK; ++rr) {
        const int row = blockIdx.x * ROWS_PER_BLOCK + rr;
        const float4* dvec = (const float4*)dist + (long long)row * ROW_VECS;

        double v[5];
#pragma unroll
        for (int k = 0; k < 5; ++k) v[k] = SENT;

#pragma unroll 1
        for (int half = 0; half < 4; ++half) {
            // batch 8 independent loads (4 dist float4 + 4 pot uchar4)
            float4 dd[4]; uchar4 pp[4];
#pragma unroll
            for (int g = 0; g < 4; ++g) {
                const int vi = (half * 4 + g) * 256 + tid;
                dd[g] = dvec[vi];
                pp[g] = pvec[vi];
            }
#pragma unroll
            for (int g = 0; g < 4; ++g) {
                const unsigned base =
                    (unsigned)(((half * 4 + g) * 256 + tid) * 4);
                double s0 = mkkeyd(dd[g].x, pp[g].x, base + 0);
                double s1 = mkkeyd(dd[g].y, pp[g].y, base + 1);
                double s2 = mkkeyd(dd[g].z, pp[g].z, base + 2);
                double s3 = mkkeyd(dd[g].w, pp[g].w, base + 3);
                const double gmin = fmin(fmin(s0, s1), fmin(s2, s3));
                if (__any(gmin < v[4])) {
                    // sort4: (0,1)(2,3)(0,2)(1,3)(1,2)
                    casd(s0, s1); casd(s2, s3);
                    casd(s0, s2); casd(s1, s3);
                    casd(s1, s2);
                    // merge sorted-4 (SENT pad) into running sorted-5
                    double m0 = v[0];
                    double m1 = fmin(v[1], s3);
                    double m2 = fmin(v[2], s2);
                    double m3 = fmin(v[3], s1);
                    double m4 = fmin(v[4], s0);
                    casd(m0, m4);
                    casd(m1, m3); casd(m2, m4);
                    casd(m1, m2); casd(m3, m4);
                    v[0] = m0; v[1] = m1; v[2] = m2; v[3] = m3; v[4] = m4;
                }
            }
        }

        // 6-stage butterfly across the wave
#pragma unroll
        for (int mask = 1; mask <= 32; mask <<= 1) {
            double b[5];
#pragma unroll
            for (int k = 0; k < 5; ++k) b[k] = __shfl_xor(v[k], mask, 64);
            merge5d(v, b);
        }

        // cross-wave via LDS; tid 0 finalizes
        const int wave = tid >> 6;
        if (wave > 0 && (tid & 63) == 0) {
#pragma unroll
            for (int k = 0; k < 5; ++k) sv[wave - 1][k] = v[k];
        }
        __syncthreads();
        if (tid == 0) {
            double b[5];
#pragma unroll
            for (int w = 0; w < 3; ++w) {
                b[0] = sv[w][0]; b[1] = sv[w][1]; b[2] = sv[w][2];
                b[3] = sv[w][3]; b[4] = sv[w][4];
                merge5d(v, b);
            }
#pragma unroll
            for (int k = 0; k < 5; ++k)
                wslists[(long long)row * 5 + k] =
                    (u64)__double_as_longlong(v[k]);
        }
        __syncthreads();   // sv reused next row
    }
}

// ---------------------------------------------------------------------------
// Pass 2 (fused): coalesced float4 copy of X->out; the lane owning each
// row's first float4 runs the epilogue (validated rounds 6-13) and patches .x.
// ---------------------------------------------------------------------------
__global__ __launch_bounds__(256) void pass2_kernel(
    const float* __restrict__ X,
    const u64* __restrict__ wslists,
    const void* __restrict__ maskp,
    const void* __restrict__ mkfitp,
    const float* __restrict__ fitX,
    const int* __restrict__ dmap,
    const int* __restrict__ wflagp,
    const float* __restrict__ cmeanp,
    const unsigned char* __restrict__ inmiss,
    const unsigned char* __restrict__ pot8,
    float* __restrict__ out)
{
    const int gid = blockIdx.x * 256 + threadIdx.x;    // 0..32767
    if (gid >= NQ * DD / 4) return;
    float4 v4 = ((const float4*)X)[gid];

    if ((gid & 7) == 0) {
        const int r = gid >> 3;
        const int q = dmap[r];
        u64 v[5];
        const u64* lp = wslists + (long long)q * 5;
#pragma unroll
        for (int i = 0; i < 5; ++i) v[i] = lp[i];

        const int w32 = *wflagp;
        const bool has_valid = (unsigned)(v[0] >> 32) < __float_as_uint(BIGF);
        const bool receiver =
            inmiss[r] && boolat(maskp, (long long)r * DD + COLIDX, w32);

        float val;
        if (!receiver) {
            val = v4.x;                    // X[r*DD+0]
        } else if (!has_valid) {
            val = *cmeanp;
        } else {
            float keyf[5]; bool ok[5]; int idxc[5];
#pragma unroll
            for (int i = 0; i < 5; ++i) {
                keyf[i] = __uint_as_float((unsigned)(v[i] >> 32));
                const unsigned id = (unsigned)(v[i] & 0xFFFFFFFFu);
                ok[i] = id < NT;
                idxc[i] = ok[i] ? (int)id : 0;
            }
            float dnr[5]; int mfv[5]; unsigned char vldb[5];
#pragma unroll
            for (int i = 0; i < 5; ++i)
                dnr[i] = fitX[(long long)idxc[i] * DD + COLIDX];
#pragma unroll
            for (int i = 0; i < 5; ++i)
                mfv[i] = boolat(mkfitp, (long long)idxc[i] * DD + COLIDX, w32);
#pragma unroll
            for (int i = 0; i < 5; ++i) vldb[i] = pot8[idxc[i]];

            float wk[5];
            bool infrow = false;
#pragma unroll
            for (int i = 0; i < 5; ++i) {
                const float dpot = (keyf[i] == BIGF) ? __builtin_nanf("") : keyf[i];
                const float t = 1.0f / dpot;     // 0->inf, inf->0, NaN->NaN
                wk[i] = ok[i] ? t : 0.0f;
                if (ok[i] && isinf(t)) infrow = true;
            }
            if (infrow) {
#pragma unroll
                for (int i = 0; i < 5; ++i) wk[i] = isinf(wk[i]) ? 1.0f : 0.0f;
            }
#pragma unroll
            for (int i = 0; i < 5; ++i) if (wk[i] != wk[i]) wk[i] = 0.0f;

            float wsum = 0.0f, vsum = 0.0f;
#pragma unroll
            for (int i = 0; i < 5; ++i) {
                const float dm = ok[i] ? (1.0f - (float)mfv[i]) : 0.0f;
                const float vl = ok[i] ? (float)vldb[i] : 0.0f;
                const float nw = dm * wk[i] * vl;
                wsum += nw;
                vsum += dnr[i] * nw;
            }
            const float div = (wsum == 0.0f) ? 1.0f : wsum;
            val = vsum / div;
        }
        v4.x = val;
    }
    ((float4*)out)[gid] = v4;
}

extern "C" void kernel_launch(void* const* d_in, const int* in_sizes, int n_in,
                              void* d_out, int out_size, void* d_ws, size_t ws_size,
                              hipStream_t stream) {
    const float* X     = (const float*)d_in[0];
    const float* dist  = (const float*)d_in[1];
    const void*  nm    = d_in[2];   // non_missing_fix_X (bool)
    const void*  mkfit = d_in[3];   // mask_fit_X (bool)
    const int*   dmap  = (const int*)d_in[4];
    const void*  maskp = d_in[5];   // mask (bool)
    const int*   rmi   = (const int*)d_in[6];
    const float* fitX  = (const float*)d_in[7];
    float* out = (float*)d_out;

    // workspace layout (all 4-byte aligned)
    u64*   wslists = (u64*)d_ws;                               // 4096*40 B
    char*  base    = (char*)d_ws + (size_t)NQ * 5 * 8;
    int*   wflag   = (int*)base;
    float* cmean   = (float*)(base + 4);
    float* partial = (float*)(base + 8);                       // 512 B
    unsigned char* inmiss = (unsigned char*)base + 520;        // NQ bytes
    unsigned char* pot8   = (unsigned char*)base + 520 + NQ;   // NT bytes

    prep1_kernel<<<64, 256, 0, stream>>>(nm, mkfit, fitX, wflag, partial,
                                         inmiss, pot8);
    prep2_kernel<<<1, 256, 0, stream>>>(rmi, partial, cmean, inmiss);
    pass1_kernel<<<P1_BLOCKS, 256, 0, stream>>>(dist, pot8, wslists);
    pass2_kernel<<<(NQ * DD / 4 + 255) / 256, 256, 0, stream>>>(
        X, wslists, maskp, mkfit, fitX, dmap, wflag, cmean, inmiss, pot8, out);
}

// Round 15
// 63.387 us; speedup vs baseline: 1.0750x; 1.0750x over previous
//
#include <hip/hip_runtime.h>
#include <math.h>

#define NQ 4096
#define NT 16384
#define DD 32
#define COLIDX 0
#define BIGF 1.0e10f
#define INFF __builtin_inff()

typedef unsigned long long u64;

#define ROW_VECS (NT / 4)                 // 4096 float4 per row
#define ROWS_PER_BLOCK 2
#define P1_BLOCKS (NQ / ROWS_PER_BLOCK)   // 2048 blocks = 8 blocks/CU

// Sentinel: larger (as u64/f64) than any real packed key; positive non-NaN f64.
#define SENT_BITS 0x7F800000FFFFFFFFULL

// ---------------------------------------------------------------------------
// bool-width helpers (unknown numpy bool storage: u8 vs i32)
// ---------------------------------------------------------------------------
__device__ __forceinline__ int boolat(const void* p, long long idx, int w32) {
    if (w32) return ((const int*)p)[idx] != 0;
    return ((const unsigned char*)p)[idx] != 0;
}

__device__ __forceinline__ int detect_w32(const void* nm, const void* mk,
                                          int tid, int* s_bad) {
    if (tid == 0) *s_bad = 0;
    __syncthreads();
    const unsigned char* nm8 = (const unsigned char*)nm;
    const unsigned char* mk8 = (const unsigned char*)mk;
    int bad = 0;
    for (int b = tid; b < 4096; b += 256)
        if ((int)nm8[b] + (int)mk8[b] != 1) bad = 1;
    if (bad) atomicOr(s_bad, 1);
    __syncthreads();
    return *s_bad ? 1 : 0;
}

// ---------------------------------------------------------------------------
// prep1: 64 blocks x 256 threads — pot8 pack, colmean partials, inmiss clear,
// PLUS grid-stride bulk copy X->out (validated logic, moved from pass2).
// ---------------------------------------------------------------------------
__global__ __launch_bounds__(256) void prep1_kernel(
    const void* __restrict__ nm, const void* __restrict__ mk,
    const float* __restrict__ fitX, const float* __restrict__ X,
    int* __restrict__ wflag, float* __restrict__ partial,
    unsigned char* __restrict__ inmiss, unsigned char* __restrict__ pot8,
    float* __restrict__ out)
{
    __shared__ int s_bad;
    __shared__ float sc[256], sm[256];
    const int tid = threadIdx.x;
    const int w32 = detect_w32(nm, mk, tid, &s_bad);
    if (blockIdx.x == 0 && tid == 0) *wflag = w32;

    const int t = blockIdx.x * 256 + tid;          // 0..16383
    pot8[t] = (unsigned char)boolat(nm, (long long)t * DD + COLIDX, w32);

    float cs = 0.0f, ms = 0.0f;
    if (!boolat(mk, (long long)t * DD + COLIDX, w32)) {
        cs = fitX[(long long)t * DD + COLIDX];
        ms = 1.0f;
    }
    sc[tid] = cs; sm[tid] = ms;
    __syncthreads();
#pragma unroll
    for (int s = 128; s > 0; s >>= 1) {
        if (tid < s) { sc[tid] += sc[tid + s]; sm[tid] += sm[tid + s]; }
        __syncthreads();
    }
    if (tid == 0) { partial[blockIdx.x * 2] = sc[0]; partial[blockIdx.x * 2 + 1] = sm[0]; }

    if (t < NQ) inmiss[t] = 0;

    // bulk copy X -> out (col 0 words patched later by pass2)
    const float4* Xv = (const float4*)X;
    float4* outv = (float4*)out;
    for (int i = t; i < NQ * DD / 4; i += 64 * 256)
        outv[i] = Xv[i];
}

// ---------------------------------------------------------------------------
// f64-packed key trick (validated rounds 13-14): packed (key_bits<<32)|idx
// viewed as double is always a POSITIVE NON-NAN f64 (NaN f32 keys excluded
// by fminf) -> numeric order == bit order == exact (key asc, idx asc)
// jax.lax.top_k order. v_min/max_f64 = 1 inst vs 3/5 for u64 cmp+selects.
// ---------------------------------------------------------------------------
__device__ __forceinline__ double mkkeyd(float d, unsigned char p, unsigned idx) {
    const float key = (p != 0) ? fminf(d, BIGF) : INFF;  // NaN->BIG; !pot->INF
    const u64 bits = ((u64)__float_as_uint(key) << 32) | (u64)idx;
    return __longlong_as_double((long long)bits);
}

__device__ __forceinline__ void casd(double& x, double& y) {
    const double lo = fmin(x, y);
    const double hi = fmax(x, y);
    x = lo; y = hi;
}

// Merge two ascending sorted-5 lists, keep lowest 5, output sorted
// (network validated rounds 6-14).
__device__ __forceinline__ void merge5d(double a[5], const double b[5]) {
    double m0 = fmin(a[0], b[4]);
    double m1 = fmin(a[1], b[3]);
    double m2 = fmin(a[2], b[2]);
    double m3 = fmin(a[3], b[1]);
    double m4 = fmin(a[4], b[0]);
    casd(m0, m4);
    casd(m1, m3); casd(m2, m4);
    casd(m1, m2); casd(m3, m4);
    a[0] = m0; a[1] = m1; a[2] = m2; a[3] = m3; a[4] = m4;
}

// ---------------------------------------------------------------------------
// Pass 1: round-13 structure (fastest; stream-roofline-bound). Block 0 also
// absorbs prep2's work (inmiss scatter + colmean reduce) before its rows —
// ordering safe: prep1 (clear, partials) completed; pass2 (consumer) runs
// after pass1. Saves one kernel launch.
// ---------------------------------------------------------------------------
__global__ __launch_bounds__(256, 8) void pass1_kernel(
    const float* __restrict__ dist,
    const unsigned char* __restrict__ pot8,
    const int* __restrict__ rmi,
    const float* __restrict__ partial,
    float* __restrict__ cmean,
    unsigned char* __restrict__ inmiss,
    u64* __restrict__ wslists)
{
    __shared__ double sv[3][5];
    const int tid = threadIdx.x;
    const uchar4* pvec = (const uchar4*)pot8;
    const double SENT = __longlong_as_double((long long)SENT_BITS);

    if (blockIdx.x == 0) {
        for (int i = tid; i < NQ; i += 256) {
            int r = rmi[i];
            if (r >= 0 && r < NQ) inmiss[r] = 1;
        }
        if (tid < 64) {
            float c = partial[2 * tid];
            float m = partial[2 * tid + 1];
#pragma unroll
            for (int off = 32; off >= 1; off >>= 1) {
                c += __shfl_down(c, off, 64);
                m += __shfl_down(m, off, 64);
            }
            if (tid == 0) *cmean = c / (m > 0.0f ? m : 1.0f);
        }
    }

#pragma unroll 1
    for (int rr = 0; rr < ROWS_PER_BLOCK; ++rr) {
        const int row = blockIdx.x * ROWS_PER_BLOCK + rr;
        const float4* dvec = (const float4*)dist + (long long)row * ROW_VECS;

        double v[5];
#pragma unroll
        for (int k = 0; k < 5; ++k) v[k] = SENT;

#pragma unroll 1
        for (int half = 0; half < 4; ++half) {
            // batch 8 independent loads (4 dist float4 + 4 pot uchar4)
            float4 dd[4]; uchar4 pp[4];
#pragma unroll
            for (int g = 0; g < 4; ++g) {
                const int vi = (half * 4 + g) * 256 + tid;
                dd[g] = dvec[vi];
                pp[g] = pvec[vi];
            }
#pragma unroll
            for (int g = 0; g < 4; ++g) {
                const unsigned base =
                    (unsigned)(((half * 4 + g) * 256 + tid) * 4);
                double s0 = mkkeyd(dd[g].x, pp[g].x, base + 0);
                double s1 = mkkeyd(dd[g].y, pp[g].y, base + 1);
                double s2 = mkkeyd(dd[g].z, pp[g].z, base + 2);
                double s3 = mkkeyd(dd[g].w, pp[g].w, base + 3);
                // sort4: (0,1)(2,3)(0,2)(1,3)(1,2)
                casd(s0, s1); casd(s2, s3);
                casd(s0, s2); casd(s1, s3);
                casd(s1, s2);
                // merge sorted-4 (SENT pad) into running sorted-5
                double m0 = v[0];
                double m1 = fmin(v[1], s3);
                double m2 = fmin(v[2], s2);
                double m3 = fmin(v[3], s1);
                double m4 = fmin(v[4], s0);
                casd(m0, m4);
                casd(m1, m3); casd(m2, m4);
                casd(m1, m2); casd(m3, m4);
                v[0] = m0; v[1] = m1; v[2] = m2; v[3] = m3; v[4] = m4;
            }
        }

        // 6-stage butterfly across the wave
#pragma unroll
        for (int mask = 1; mask <= 32; mask <<= 1) {
            double b[5];
#pragma unroll
            for (int k = 0; k < 5; ++k) b[k] = __shfl_xor(v[k], mask, 64);
            merge5d(v, b);
        }

        // cross-wave via LDS; tid 0 finalizes
        const int wave = tid >> 6;
        if (wave > 0 && (tid & 63) == 0) {
#pragma unroll
            for (int k = 0; k < 5; ++k) sv[wave - 1][k] = v[k];
        }
        __syncthreads();
        if (tid == 0) {
            double b[5];
#pragma unroll
            for (int w = 0; w < 3; ++w) {
                b[0] = sv[w][0]; b[1] = sv[w][1]; b[2] = sv[w][2];
                b[3] = sv[w][3]; b[4] = sv[w][4];
                merge5d(v, b);
            }
#pragma unroll
            for (int k = 0; k < 5; ++k)
                wslists[(long long)row * 5 + k] =
                    (u64)__double_as_longlong(v[k]);
        }
        __syncthreads();   // sv reused next row
    }
}

// ---------------------------------------------------------------------------
// Pass 2 (patch-only): one thread per row — epilogue (validated rounds 6-14)
// and a single scalar store to out[r*DD]. Bulk copy already done by prep1.
// ---------------------------------------------------------------------------
__global__ __launch_bounds__(256) void pass2_kernel(
    const float* __restrict__ X,
    const u64* __restrict__ wslists,
    const void* __restrict__ maskp,
    const void* __restrict__ mkfitp,
    const float* __restrict__ fitX,
    const int* __restrict__ dmap,
    const int* __restrict__ wflagp,
    const float* __restrict__ cmeanp,
    const unsigned char* __restrict__ inmiss,
    const unsigned char* __restrict__ pot8,
    float* __restrict__ out)
{
    const int r = blockIdx.x * 256 + threadIdx.x;
    if (r >= NQ) return;

    const int q = dmap[r];
    u64 v[5];
    const u64* lp = wslists + (long long)q * 5;
#pragma unroll
    for (int i = 0; i < 5; ++i) v[i] = lp[i];

    const int w32 = *wflagp;
    const bool has_valid = (unsigned)(v[0] >> 32) < __float_as_uint(BIGF);
    const bool receiver =
        inmiss[r] && boolat(maskp, (long long)r * DD + COLIDX, w32);

    float val;
    if (!receiver) {
        val = X[(long long)r * DD + COLIDX];
    } else if (!has_valid) {
        val = *cmeanp;
    } else {
        float keyf[5]; bool ok[5]; int idxc[5];
#pragma unroll
        for (int i = 0; i < 5; ++i) {
            keyf[i] = __uint_as_float((unsigned)(v[i] >> 32));
            const unsigned id = (unsigned)(v[i] & 0xFFFFFFFFu);
            ok[i] = id < NT;
            idxc[i] = ok[i] ? (int)id : 0;
        }
        float dnr[5]; int mfv[5]; unsigned char vldb[5];
#pragma unroll
        for (int i = 0; i < 5; ++i)
            dnr[i] = fitX[(long long)idxc[i] * DD + COLIDX];
#pragma unroll
        for (int i = 0; i < 5; ++i)
            mfv[i] = boolat(mkfitp, (long long)idxc[i] * DD + COLIDX, w32);
#pragma unroll
        for (int i = 0; i < 5; ++i) vldb[i] = pot8[idxc[i]];

        float wk[5];
        bool infrow = false;
#pragma unroll
        for (int i = 0; i < 5; ++i) {
            const float dpot = (keyf[i] == BIGF) ? __builtin_nanf("") : keyf[i];
            const float t = 1.0f / dpot;     // 0->inf, inf->0, NaN->NaN
            wk[i] = ok[i] ? t : 0.0f;
            if (ok[i] && isinf(t)) infrow = true;
        }
        if (infrow) {
#pragma unroll
            for (int i = 0; i < 5; ++i) wk[i] = isinf(wk[i]) ? 1.0f : 0.0f;
        }
#pragma unroll
        for (int i = 0; i < 5; ++i) if (wk[i] != wk[i]) wk[i] = 0.0f;

        float wsum = 0.0f, vsum = 0.0f;
#pragma unroll
        for (int i = 0; i < 5; ++i) {
            const float dm = ok[i] ? (1.0f - (float)mfv[i]) : 0.0f;
            const float vl = ok[i] ? (float)vldb[i] : 0.0f;
            const float nw = dm * wk[i] * vl;
            wsum += nw;
            vsum += dnr[i] * nw;
        }
        const float div = (wsum == 0.0f) ? 1.0f : wsum;
        val = vsum / div;
    }
    out[(long long)r * DD + COLIDX] = val;
}

extern "C" void kernel_launch(void* const* d_in, const int* in_sizes, int n_in,
                              void* d_out, int out_size, void* d_ws, size_t ws_size,
                              hipStream_t stream) {
    const float* X     = (const float*)d_in[0];
    const float* dist  = (const float*)d_in[1];
    const void*  nm    = d_in[2];   // non_missing_fix_X (bool)
    const void*  mkfit = d_in[3];   // mask_fit_X (bool)
    const int*   dmap  = (const int*)d_in[4];
    const void*  maskp = d_in[5];   // mask (bool)
    const int*   rmi   = (const int*)d_in[6];
    const float* fitX  = (const float*)d_in[7];
    float* out = (float*)d_out;

    // workspace layout (all 4-byte aligned)
    u64*   wslists = (u64*)d_ws;                               // 4096*40 B
    char*  base    = (char*)d_ws + (size_t)NQ * 5 * 8;
    int*   wflag   = (int*)base;
    float* cmean   = (float*)(base + 4);
    float* partial = (float*)(base + 8);                       // 512 B
    unsigned char* inmiss = (unsigned char*)base + 520;        // NQ bytes
    unsigned char* pot8   = (unsigned char*)base + 520 + NQ;   // NT bytes

    prep1_kernel<<<64, 256, 0, stream>>>(nm, mkfit, fitX, X, wflag, partial,
                                         inmiss, pot8, out);
    pass1_kernel<<<P1_BLOCKS, 256, 0, stream>>>(dist, pot8, rmi, partial,
                                                cmean, inmiss, wslists);
    pass2_kernel<<<(NQ + 255) / 256, 256, 0, stream>>>(
        X, wslists, maskp, mkfit, fitX, dmap, wflag, cmean, inmiss, pot8, out);
}